// Round 1
// baseline (569.081 us; speedup 1.0000x reference)
//
#include <hip/hip_runtime.h>

// Linear-chain CRF log-partition (backward DP), B=64, S=1024, T=128.
//
// r12 = single-wave redesign of r11 (431us).
//
// Theory: the problem is latency-bound on a 1024-step serial chain
// (per-step ~1010 cyc, VALU issue only ~130 of them). r11's 4-wave split
// paid ds_write drain + s_barrier + LDS read latency + 2-stage DPP quad
// reduction on EVERY step of the serial chain. r12 gives the whole
// 128x128 matvec to ONE wave (lane l owns rows 2l,2l+1, all 128 cols,
// E in 128 VGPRs; waves_per_eu(1,1) -> 512-VGPR budget):
//   - no s_barrier anywhere (single wave, lockstep; lgkmcnt ordering only)
//   - no parity double-buffer (WAR protected by reads->dots->q->v' dep)
//   - gather = 16 uniform-address ds_read_b128 (broadcast, conflict-free,
//     DS pipe overlaps the 128 v_dot2 on the VALU pipe)
//   - no cross-lane reduction: each lane's accumulators ARE the row sums
//   - z via readfirstlane instead of the zslot LDS round-trip
//
// Numerics identical in structure to r11 (proven passing): publish
// v' = q*u*e^{-GHAT} (f16, no feedback); q <- (E v')*rcp(z) with
// z = previous step's row-0 value; Lam += GHAT + log z. Only the
// accumulation association changes (4 accs over 64 terms vs 16+DPP).

typedef _Float16 h2 __attribute__((ext_vector_type(2)));

#define B_  64
#define S_  1024
#define T_  128
#define PAD_IDX 0
#define EOS_IDX 3
#define BOT_IDX 1
#define GHAT         5.35f
#define EXP_NEG_GHAT 0.004736892f   // e^{-5.35}

#if defined(__has_builtin)
#if __has_builtin(__builtin_amdgcn_fdot2)
#define HAS_FDOT2 1
#endif
#endif

static __device__ __forceinline__ float dot2acc(unsigned eu, unsigned pu, float c) {
  h2 a = __builtin_bit_cast(h2, eu);
  h2 b = __builtin_bit_cast(h2, pu);
#ifdef HAS_FDOT2
  return __builtin_amdgcn_fdot2(a, b, c, false);
#else
  return fmaf((float)a.x, (float)b.x, fmaf((float)a.y, (float)b.y, c));
#endif
}

__global__ __launch_bounds__(64)
__attribute__((amdgpu_waves_per_eu(1, 1)))
void crf_logz_kernel(
    const int*   __restrict__ W,
    const float* __restrict__ emissions,
    const float* __restrict__ transitions,
    float*       __restrict__ out)
{
  const int b  = blockIdx.x;
  const int l  = threadIdx.x;        // 0..63 — exactly one wave
  const int rA = 2 * l;              // this lane owns rows rA, rA+1

  __shared__ __align__(16) unsigned vbuf[T_ / 2];   // 64 packed f16 pairs (256 B)

  // ---- E rows rA, rA+1, ALL 128 cols as packed f16 pairs (128 VGPRs)
  unsigned EuA[64], EuB[64];
  {
    const float2* ta = (const float2*)(transitions + (size_t)rA * T_);
    const float2* tb = (const float2*)(transitions + (size_t)(rA + 1) * T_);
    #pragma unroll
    for (int k = 0; k < 64; ++k) {
      float2 x = ta[k], y = tb[k];
      h2 ex, ey;
      ex.x = (_Float16)__expf(x.x); ex.y = (_Float16)__expf(x.y);
      ey.x = (_Float16)__expf(y.x); ey.y = (_Float16)__expf(y.y);
      EuA[k] = __builtin_bit_cast(unsigned, ex);
      EuB[k] = __builtin_bit_cast(unsigned, ey);
    }
  }

  const int*    Wrow = W + b * S_;
  const float2* emb2 = (const float2*)(emissions + (size_t)b * S_ * T_) + l;

  float2 q;  q.x = 1.0f; q.y = 1.0f;   // exp-state rows rA, rA+1
  float  Lam = 0.0f;
  float  z   = 1.0f;                   // previous row-0 value (uniform)

  // 4-deep em prefetch: slot0 holds consumed index i
  float2 e0 = emb2[(size_t)(S_ - 1) * 64];
  float2 e1 = emb2[(size_t)(S_ - 2) * 64];
  float2 e2 = emb2[(size_t)(S_ - 3) * 64];
  float2 e3 = emb2[(size_t)(S_ - 4) * 64];
  float2 us0, us1;
  us0.x = __expf(e0.x) * EXP_NEG_GHAT; us0.y = __expf(e0.y) * EXP_NEG_GHAT;
  us1.x = __expf(e1.x) * EXP_NEG_GHAT; us1.y = __expf(e1.y) * EXP_NEG_GHAT;

  for (int c = 15; c >= 0; --c) {
    // one vector load of 64 token ids -> uniform 64-bit activity mask (SGPRs)
    int wtok = Wrow[(c << 6) + l];
    unsigned long long m = __ballot((wtok != PAD_IDX) & (wtok != EOS_IDX));
    const int lo = (c == 0) ? 1 : 0;          // i==0 is never consumed

    #pragma unroll 2
    for (int bit = 63; bit >= lo; --bit) {
      const int i = (c << 6) + bit;           // consumed emission index
      int pf = i - 4; pf &= ~(pf >> 31);      // max(i-4, 0): tail re-read is harmless
      float2 en = emb2[(size_t)pf * 64];      // prefetch (vmcnt, not drained)

      const bool active = (long long)m < 0;   // top bit; wave-uniform
      m <<= 1;

      if (active) {
        // publish v' = q .* us  (each lane writes its own packed pair)
        h2 vh; vh.x = (_Float16)(q.x * us0.x); vh.y = (_Float16)(q.y * us0.y);
        vbuf[l] = __builtin_bit_cast(unsigned, vh);

        float rz = __builtin_amdgcn_rcpf(z);  // uniform; off the dot chain
        Lam += GHAT + __logf(z);              // exact compensation (off-path)

        // gather ALL of v' (uniform-address broadcast reads, conflict-free);
        // lgkmcnt ordering by the compiler — no barrier (single wave)
        const uint4* vb = (const uint4*)vbuf;
        float aA0=0.f,aA1=0.f,aA2=0.f,aA3=0.f;
        float aB0=0.f,aB1=0.f,aB2=0.f,aB3=0.f;
        #pragma unroll
        for (int k = 0; k < 16; ++k) {
          uint4 pv = vb[k];                   // pairs 4k..4k+3 = cols 8k..8k+7
          aA0 = dot2acc(EuA[4*k+0], pv.x, aA0);
          aA1 = dot2acc(EuA[4*k+1], pv.y, aA1);
          aA2 = dot2acc(EuA[4*k+2], pv.z, aA2);
          aA3 = dot2acc(EuA[4*k+3], pv.w, aA3);
          aB0 = dot2acc(EuB[4*k+0], pv.x, aB0);
          aB1 = dot2acc(EuB[4*k+1], pv.y, aB1);
          aB2 = dot2acc(EuB[4*k+2], pv.z, aB2);
          aB3 = dot2acc(EuB[4*k+3], pv.w, aB3);
        }
        float sA = (aA0 + aA1) + (aA2 + aA3); // complete row sums — no DPP
        float sB = (aB0 + aB1) + (aB2 + aB3);

        q.x = sA * rz;
        q.y = sB * rz;
        // next-step normalizer = new row-0 value (lane 0's q.x)
        z = __builtin_bit_cast(float,
              __builtin_amdgcn_readfirstlane(__builtin_bit_cast(int, q.x)));
      }
      // shift prefetch pipeline
      e0 = e1; us0 = us1;
      e1 = e2;
      e2 = e3;
      e3 = en;
      us1.x = __expf(e1.x) * EXP_NEG_GHAT;
      us1.y = __expf(e1.y) * EXP_NEG_GHAT;
    }
  }

  // ---- epilogue: f_r = trans[BOT,r] + em[b,0,r] + log q_r; logZ = Lam + LSE(f)
  float2 tb2 = *(const float2*)(transitions + (size_t)BOT_IDX * T_ + rA);
  float fx = tb2.x + e0.x + __logf(q.x);      // e0 ended as em[b,0,rA..rA+1]
  float fy = tb2.y + e0.y + __logf(q.y);
  float mx = fmaxf(fx, fy);
  #pragma unroll
  for (int off = 32; off; off >>= 1) mx = fmaxf(mx, __shfl_xor(mx, off));
  float s = __expf(fx - mx) + __expf(fy - mx);
  #pragma unroll
  for (int off = 32; off; off >>= 1) s += __shfl_xor(s, off);
  if (l == 0) out[b] = Lam + mx + __logf(s);
}

extern "C" void kernel_launch(void* const* d_in, const int* in_sizes, int n_in,
                              void* d_out, int out_size, void* d_ws, size_t ws_size,
                              hipStream_t stream) {
  const int*   W     = (const int*)d_in[0];
  const float* em    = (const float*)d_in[1];
  const float* trans = (const float*)d_in[2];
  float*       out   = (float*)d_out;
  (void)in_sizes; (void)n_in; (void)out_size; (void)d_ws; (void)ws_size;
  crf_logz_kernel<<<B_, 64, 0, stream>>>(W, em, trans, out);
}

// Round 2
// 568.126 us; speedup vs baseline: 1.0017x; 1.0017x over previous
//
#include <hip/hip_runtime.h>

// Linear-chain CRF log-partition (backward DP), B=64, S=1024, T=128.
//
// r13 = r12 (single-wave matvec) + the register-residency fix.
//
// r12 post-mortem: VGPR_Count stayed 132 although the design needs >=150
// (EuA/EuB = 128 regs). The compiler demoted the E arrays out of VGPRs,
// so every active step re-materialized ~512 B/lane of E on the serial
// chain (one active SIMD ~59% busy x ~1180 cyc ~= 700 issue-cyc/step vs
// ~300 expected). r11 prevented exactly this with per-iteration asm
// keep-alives; r12 dropped them when scaling 32->128 E regs.
//
// r13 restores the keep-alives for all 128 E registers (8 statements x
// 16 "v" operands at the top of every inner iteration). Verification
// signal: VGPR_Count must jump to >=170.
//
// Structure (unchanged from r12):
//   - ONE wave per block; lane l owns rows 2l, 2l+1, all 128 cols.
//   - no s_barrier (single wave; lgkmcnt ordering only)
//   - gather = 16 uniform-address ds_read_b128 (broadcast, conflict-free)
//   - no cross-lane reduction; z via readfirstlane
// Numerics identical to r11/r12 (both passed, absmax 0.0): publish
// v' = q*u*e^{-GHAT} (f16); q <- (E v')*rcp(z); Lam += GHAT + log z.

typedef _Float16 h2 __attribute__((ext_vector_type(2)));

#define B_  64
#define S_  1024
#define T_  128
#define PAD_IDX 0
#define EOS_IDX 3
#define BOT_IDX 1
#define GHAT         5.35f
#define EXP_NEG_GHAT 0.004736892f   // e^{-5.35}

#if defined(__has_builtin)
#if __has_builtin(__builtin_amdgcn_fdot2)
#define HAS_FDOT2 1
#endif
#endif

static __device__ __forceinline__ float dot2acc(unsigned eu, unsigned pu, float c) {
  h2 a = __builtin_bit_cast(h2, eu);
  h2 b = __builtin_bit_cast(h2, pu);
#ifdef HAS_FDOT2
  return __builtin_amdgcn_fdot2(a, b, c, false);
#else
  return fmaf((float)a.x, (float)b.x, fmaf((float)a.y, (float)b.y, c));
#endif
}

// Force 16 values to be simultaneously resident in VGPRs (zero instructions).
#define KEEP16(A, o) \
  asm volatile("" :: "v"(A[(o)+0]),  "v"(A[(o)+1]),  "v"(A[(o)+2]),  "v"(A[(o)+3]),  \
                     "v"(A[(o)+4]),  "v"(A[(o)+5]),  "v"(A[(o)+6]),  "v"(A[(o)+7]),  \
                     "v"(A[(o)+8]),  "v"(A[(o)+9]),  "v"(A[(o)+10]), "v"(A[(o)+11]), \
                     "v"(A[(o)+12]), "v"(A[(o)+13]), "v"(A[(o)+14]), "v"(A[(o)+15]))

__global__ __launch_bounds__(64)
__attribute__((amdgpu_waves_per_eu(1, 1)))
void crf_logz_kernel(
    const int*   __restrict__ W,
    const float* __restrict__ emissions,
    const float* __restrict__ transitions,
    float*       __restrict__ out)
{
  const int b  = blockIdx.x;
  const int l  = threadIdx.x;        // 0..63 — exactly one wave
  const int rA = 2 * l;              // this lane owns rows rA, rA+1

  __shared__ __align__(16) unsigned vbuf[T_ / 2];   // 64 packed f16 pairs (256 B)

  // ---- E rows rA, rA+1, ALL 128 cols as packed f16 pairs (128 VGPRs)
  unsigned EuA[64], EuB[64];
  {
    const float2* ta = (const float2*)(transitions + (size_t)rA * T_);
    const float2* tb = (const float2*)(transitions + (size_t)(rA + 1) * T_);
    #pragma unroll
    for (int k = 0; k < 64; ++k) {
      float2 x = ta[k], y = tb[k];
      h2 ex, ey;
      ex.x = (_Float16)__expf(x.x); ex.y = (_Float16)__expf(x.y);
      ey.x = (_Float16)__expf(y.x); ey.y = (_Float16)__expf(y.y);
      EuA[k] = __builtin_bit_cast(unsigned, ex);
      EuB[k] = __builtin_bit_cast(unsigned, ey);
    }
  }

  const int*    Wrow = W + b * S_;
  const float2* emb2 = (const float2*)(emissions + (size_t)b * S_ * T_) + l;

  float2 q;  q.x = 1.0f; q.y = 1.0f;   // exp-state rows rA, rA+1
  float  Lam = 0.0f;
  float  z   = 1.0f;                   // previous row-0 value (uniform)

  // 4-deep em prefetch: slot0 holds consumed index i
  float2 e0 = emb2[(size_t)(S_ - 1) * 64];
  float2 e1 = emb2[(size_t)(S_ - 2) * 64];
  float2 e2 = emb2[(size_t)(S_ - 3) * 64];
  float2 e3 = emb2[(size_t)(S_ - 4) * 64];
  float2 us0, us1;
  us0.x = __expf(e0.x) * EXP_NEG_GHAT; us0.y = __expf(e0.y) * EXP_NEG_GHAT;
  us1.x = __expf(e1.x) * EXP_NEG_GHAT; us1.y = __expf(e1.y) * EXP_NEG_GHAT;

  for (int c = 15; c >= 0; --c) {
    // one vector load of 64 token ids -> uniform 64-bit activity mask (SGPRs)
    int wtok = Wrow[(c << 6) + l];
    unsigned long long m = __ballot((wtok != PAD_IDX) & (wtok != EOS_IDX));
    const int lo = (c == 0) ? 1 : 0;          // i==0 is never consumed

    for (int bit = 63; bit >= lo; --bit) {
      // keep all 128 E registers resident (zero instructions)
      KEEP16(EuA, 0);  KEEP16(EuA, 16);  KEEP16(EuA, 32);  KEEP16(EuA, 48);
      KEEP16(EuB, 0);  KEEP16(EuB, 16);  KEEP16(EuB, 32);  KEEP16(EuB, 48);

      const int i = (c << 6) + bit;           // consumed emission index
      int pf = i - 4; pf &= ~(pf >> 31);      // max(i-4, 0): tail re-read is harmless
      float2 en = emb2[(size_t)pf * 64];      // prefetch (vmcnt, not drained)

      const bool active = (long long)m < 0;   // top bit; wave-uniform
      m <<= 1;

      if (active) {
        // publish v' = q .* us  (each lane writes its own packed pair)
        h2 vh; vh.x = (_Float16)(q.x * us0.x); vh.y = (_Float16)(q.y * us0.y);
        vbuf[l] = __builtin_bit_cast(unsigned, vh);

        float rz = __builtin_amdgcn_rcpf(z);  // uniform; off the dot chain
        Lam += GHAT + __logf(z);              // exact compensation (off-path)

        // gather ALL of v' (uniform-address broadcast reads, conflict-free);
        // lgkmcnt ordering by the compiler — no barrier (single wave)
        const uint4* vb = (const uint4*)vbuf;
        float aA0=0.f,aA1=0.f,aA2=0.f,aA3=0.f;
        float aB0=0.f,aB1=0.f,aB2=0.f,aB3=0.f;
        #pragma unroll
        for (int k = 0; k < 16; ++k) {
          uint4 pv = vb[k];                   // pairs 4k..4k+3 = cols 8k..8k+7
          aA0 = dot2acc(EuA[4*k+0], pv.x, aA0);
          aA1 = dot2acc(EuA[4*k+1], pv.y, aA1);
          aA2 = dot2acc(EuA[4*k+2], pv.z, aA2);
          aA3 = dot2acc(EuA[4*k+3], pv.w, aA3);
          aB0 = dot2acc(EuB[4*k+0], pv.x, aB0);
          aB1 = dot2acc(EuB[4*k+1], pv.y, aB1);
          aB2 = dot2acc(EuB[4*k+2], pv.z, aB2);
          aB3 = dot2acc(EuB[4*k+3], pv.w, aB3);
        }
        float sA = (aA0 + aA1) + (aA2 + aA3); // complete row sums — no DPP
        float sB = (aB0 + aB1) + (aB2 + aB3);

        q.x = sA * rz;
        q.y = sB * rz;
        // next-step normalizer = new row-0 value (lane 0's q.x)
        z = __builtin_bit_cast(float,
              __builtin_amdgcn_readfirstlane(__builtin_bit_cast(int, q.x)));
      }
      // shift prefetch pipeline
      e0 = e1; us0 = us1;
      e1 = e2;
      e2 = e3;
      e3 = en;
      us1.x = __expf(e1.x) * EXP_NEG_GHAT;
      us1.y = __expf(e1.y) * EXP_NEG_GHAT;
    }
  }

  // ---- epilogue: f_r = trans[BOT,r] + em[b,0,r] + log q_r; logZ = Lam + LSE(f)
  float2 tb2 = *(const float2*)(transitions + (size_t)BOT_IDX * T_ + rA);
  float fx = tb2.x + e0.x + __logf(q.x);      // e0 ended as em[b,0,rA..rA+1]
  float fy = tb2.y + e0.y + __logf(q.y);
  float mx = fmaxf(fx, fy);
  #pragma unroll
  for (int off = 32; off; off >>= 1) mx = fmaxf(mx, __shfl_xor(mx, off));
  float s = __expf(fx - mx) + __expf(fy - mx);
  #pragma unroll
  for (int off = 32; off; off >>= 1) s += __shfl_xor(s, off);
  if (l == 0) out[b] = Lam + mx + __logf(s);
}

extern "C" void kernel_launch(void* const* d_in, const int* in_sizes, int n_in,
                              void* d_out, int out_size, void* d_ws, size_t ws_size,
                              hipStream_t stream) {
  const int*   W     = (const int*)d_in[0];
  const float* em    = (const float*)d_in[1];
  const float* trans = (const float*)d_in[2];
  float*       out   = (float*)d_out;
  (void)in_sizes; (void)n_in; (void)out_size; (void)d_ws; (void)ws_size;
  crf_logz_kernel<<<B_, 64, 0, stream>>>(W, em, trans, out);
}